// Round 8
// baseline (2749.596 us; speedup 1.0000x reference)
//
#include <hip/hip_runtime.h>
#include <cstdint>

#define T_STEPS 2048
#define NOBS    64
#define NH      128
#define NACT    18
#define CHF     512   // 8 steps * 64 floats

__device__ __forceinline__ uint64_t rfl64(uint64_t v) {
    uint32_t lo = __builtin_amdgcn_readfirstlane((uint32_t)(v & 0xffffffffull));
    uint32_t hi = __builtin_amdgcn_readfirstlane((uint32_t)(v >> 32));
    return ((uint64_t)hi << 32) | (uint64_t)lo;
}

// Bit-exact replica of a dense sequential-k f32 FMA-chain dot restricted to
// the set bits of m (ascending j): fma(0,w,acc)==acc exactly, so skipping
// zero terms preserves bits. Loads batched 8-wide (independent ds_reads,
// one waitcnt) but ADDS stay strictly in ascending order into ONE
// accumulator via __fadd_rn (contraction- and reassociation-proof).
// Mask m is wave-uniform -> all branches are uniform, no divergence.
template<int STRIDE>
__device__ __forceinline__ float sumColsOrdered(const float* Wt, uint64_t m,
                                                int base, int col, float acc) {
    while (m) {
        float buf[8];
        int n = 0;
        uint64_t mm = m;
        #pragma unroll
        for (int i = 0; i < 8; ++i) {
            if (mm) {
                int j = __builtin_ctzll(mm); mm &= mm - 1;
                buf[i] = Wt[(base + j) * STRIDE + col];
                ++n;
            }
        }
        m = mm;
        #pragma unroll
        for (int i = 0; i < 8; ++i) {
            if (i < n) acc = __fadd_rn(acc, buf[i]);
        }
    }
    return acc;
}

__global__ __launch_bounds__(128, 1) void snn_fused(
    const float* __restrict__ x,      // [512][2048][64]
    const float* __restrict__ hs,     // [512][1][128][2]
    const float* __restrict__ W1,     // [128][64]
    const float* __restrict__ b1v,    // [128]
    const float* __restrict__ beta1,  // [128]
    const float* __restrict__ W2,     // [128][128]
    const float* __restrict__ b2v,    // [128]
    const float* __restrict__ beta2,  // [128]
    const float* __restrict__ W3,     // [18][128]
    const float* __restrict__ b3v,    // [18]
    float* __restrict__ out)          // [512][2048][18]
{
    __shared__ __align__(16) float W2T[NH * NH];    // [j][h]  64 KB
    __shared__ __align__(16) float W3T[NH * NACT];  // [j][a]  9 KB
    __shared__ __align__(16) float xbf[2][CHF];     // 4 KB double-buffered x
    __shared__ uint64_t msk1[2][2];                 // [t&1][wave]
    __shared__ uint64_t msk2[2][2];

    const int tid  = threadIdx.x;
    const int h    = tid;            // hidden unit
    const int b    = blockIdx.x;     // batch
    const int wvh  = tid >> 6;       // wave index (0: h<64, 1: h>=64)
    const bool lane0 = (tid & 63) == 0;

    // ---- one-time staging (exact copies, no arithmetic) ----
    {
        const float4* wrow = reinterpret_cast<const float4*>(W2 + h * NH);
        #pragma unroll 8
        for (int k = 0; k < 32; ++k) {
            float4 v = wrow[k];
            W2T[(4 * k + 0) * NH + h] = v.x;
            W2T[(4 * k + 1) * NH + h] = v.y;
            W2T[(4 * k + 2) * NH + h] = v.z;
            W2T[(4 * k + 3) * NH + h] = v.w;
        }
    }
    for (int idx = tid; idx < NACT * NH; idx += 128) {
        int a = idx >> 7, hh = idx & (NH - 1);
        W3T[hh * NACT + a] = W3[idx];
    }

    // W1 row of this unit in registers (64 VGPRs, f32 — exact copy)
    float w1r[NOBS];
    {
        const float4* w1p = reinterpret_cast<const float4*>(W1 + h * NOBS);
        #pragma unroll
        for (int k = 0; k < 16; ++k) {
            float4 v = w1p[k];
            w1r[4 * k + 0] = v.x;
            w1r[4 * k + 1] = v.y;
            w1r[4 * k + 2] = v.z;
            w1r[4 * k + 3] = v.w;
        }
    }

    float m1  = hs[(size_t)b * (NH * 2) + h * 2 + 0];
    float m2  = hs[(size_t)b * (NH * 2) + h * 2 + 1];
    float be1 = fminf(fmaxf(beta1[h], 0.0f), 1.0f);
    float be2 = fminf(fmaxf(beta2[h], 0.0f), 1.0f);
    float b1r = b1v[h];
    float b2r = b2v[h];
    float b3r = (h < NACT) ? b3v[h] : 0.0f;

    const float* xsrc = x + (size_t)b * (T_STEPS * NOBS);

    // prologue: chunk 0 into buf 0; chunk 1 into regs (LDS-written at t==4)
    {
        float4 v = reinterpret_cast<const float4*>(xsrc)[h];
        reinterpret_cast<float4*>(&xbf[0][0])[h] = v;
    }
    float4 sA = reinterpret_cast<const float4*>(xsrc + CHF)[h];
    __syncthreads();

    for (int t = 0; t < T_STEPS; ++t) {
        const int tb = t & 1;
        const int cb = (t >> 3) & 1;

        // async stage: write chunk c+1 mid-chunk, then issue c+2 loads
        if ((t & 7) == 4) {
            if (t < T_STEPS - 8) {
                reinterpret_cast<float4*>(&xbf[cb ^ 1][0])[h] = sA;
            }
            if (t < T_STEPS - 16) {
                sA = reinterpret_cast<const float4*>(
                         xsrc + ((size_t)((t >> 3) + 2)) * CHF)[h];
            }
        }

        // ---- layer 1: strict sequential-k FMA chain (sgemm microkernel
        // order), single accumulator from 0, bias added LAST (separate
        // rounded add) — mirrors np/XLA `x @ W1.T + b1`. ----
        const float4* xr4 =
            reinterpret_cast<const float4*>(&xbf[cb][(t & 7) * NOBS]);
        float acc = 0.0f;
        #pragma unroll
        for (int k = 0; k < 16; ++k) {
            float4 xv = xr4[k];
            acc = fmaf(w1r[4 * k + 0], xv.x, acc);
            acc = fmaf(w1r[4 * k + 1], xv.y, acc);
            acc = fmaf(w1r[4 * k + 2], xv.z, acc);
            acc = fmaf(w1r[4 * k + 3], xv.w, acc);
        }
        float c1 = __fadd_rn(acc, b1r);

        // LIF 1: reset from OLD mem; update as three SEPARATELY-ROUNDED ops
        // (reference: beta*mem + cur - reset, no fma contraction).
        {
            float r1 = (m1 > 1.0f) ? 1.0f : 0.0f;
            float t1 = __fmul_rn(be1, m1);
            float t2 = __fadd_rn(t1, c1);
            m1 = __fsub_rn(t2, r1);
        }
        uint64_t bal1 = __ballot(m1 > 1.0f);
        if (lane0) msk1[tb][wvh] = bal1;
        __syncthreads();

        // ---- layer 2: ascending-j ordered column sum (== dense sequential
        // FMA chain bit-exactly), bias last ----
        {
            uint64_t mlo = rfl64(msk1[tb][0]);
            uint64_t mhi = rfl64(msk1[tb][1]);
            float a2 = 0.0f;
            a2 = sumColsOrdered<NH>(W2T, mlo, 0,  h, a2);
            a2 = sumColsOrdered<NH>(W2T, mhi, 64, h, a2);
            float c2 = __fadd_rn(a2, b2r);

            float r2 = (m2 > 1.0f) ? 1.0f : 0.0f;
            float t1 = __fmul_rn(be2, m2);
            float t2 = __fadd_rn(t1, c2);
            m2 = __fsub_rn(t2, r2);
        }
        uint64_t bal2 = __ballot(m2 > 1.0f);
        if (lane0) msk2[tb][wvh] = bal2;
        __syncthreads();

        // ---- layer 3: ascending-j ordered sum, bias last ----
        if (h < NACT) {
            uint64_t nlo = rfl64(msk2[tb][0]);
            uint64_t nhi = rfl64(msk2[tb][1]);
            float a3 = 0.0f;
            a3 = sumColsOrdered<NACT>(W3T, nlo, 0,  h, a3);
            a3 = sumColsOrdered<NACT>(W3T, nhi, 64, h, a3);
            out[((size_t)b * T_STEPS + t) * NACT + h] = __fadd_rn(a3, b3r);
        }
    }
}

extern "C" void kernel_launch(void* const* d_in, const int* in_sizes, int n_in,
                              void* d_out, int out_size, void* d_ws, size_t ws_size,
                              hipStream_t stream) {
    const float* x     = (const float*)d_in[0];
    const float* hs    = (const float*)d_in[1];
    const float* W1    = (const float*)d_in[2];
    const float* b1    = (const float*)d_in[3];
    const float* beta1 = (const float*)d_in[4];
    const float* W2    = (const float*)d_in[5];
    const float* b2    = (const float*)d_in[6];
    const float* beta2 = (const float*)d_in[7];
    const float* W3    = (const float*)d_in[8];
    const float* b3    = (const float*)d_in[9];
    float* outp = (float*)d_out;

    snn_fused<<<dim3(512), dim3(128), 0, stream>>>(
        x, hs, W1, b1, beta1, W2, b2, beta2, W3, b3, outp);
}